// Round 1
// baseline (1408.094 us; speedup 1.0000x reference)
//
#include <hip/hip_runtime.h>

#define D 64
#define F 128

// ---------------- CSR build ----------------

__global__ void count_deg_kernel(const int* __restrict__ dst, int* __restrict__ deg, int E) {
    int i = blockIdx.x * blockDim.x + threadIdx.x;
    if (i < E) atomicAdd(&deg[dst[i]], 1);
}

// Single-block prefix scan: deg[0..n) -> row_ptr[0..n], row_ptr[0]=0, inclusive into row_ptr[i+1].
__global__ __launch_bounds__(1024) void scan_kernel(const int* __restrict__ deg,
                                                    int* __restrict__ row_ptr, int n) {
    __shared__ int wsum[16];
    int lane = threadIdx.x & 63;
    int wid  = threadIdx.x >> 6;
    int carry = 0;
    const int CH = 4096;  // 1024 threads x 4 elements
    for (int base = 0; base < n; base += CH) {
        int i0 = base + (int)threadIdx.x * 4;
        int v0 = (i0     < n) ? deg[i0]     : 0;
        int v1 = (i0 + 1 < n) ? deg[i0 + 1] : 0;
        int v2 = (i0 + 2 < n) ? deg[i0 + 2] : 0;
        int v3 = (i0 + 3 < n) ? deg[i0 + 3] : 0;
        int p0 = v0, p1 = p0 + v1, p2 = p1 + v2, p3 = p2 + v3;
        int tsum = p3;
        // wave-inclusive scan of tsum (no barriers needed within wave)
        int s = tsum;
        #pragma unroll
        for (int off = 1; off < 64; off <<= 1) {
            int t = __shfl_up(s, off);
            if (lane >= off) s += t;
        }
        if (lane == 63) wsum[wid] = s;
        __syncthreads();
        int wbase = 0, chunk_total = 0;
        #pragma unroll
        for (int w = 0; w < 16; ++w) {
            int t = wsum[w];
            chunk_total += t;
            if (w < wid) wbase += t;
        }
        __syncthreads();  // protect wsum before next chunk overwrites
        int ex = carry + wbase + (s - tsum);  // exclusive prefix for this thread's 4 elems
        if (i0     < n) row_ptr[i0 + 1] = ex + p0;
        if (i0 + 1 < n) row_ptr[i0 + 2] = ex + p1;
        if (i0 + 2 < n) row_ptr[i0 + 3] = ex + p2;
        if (i0 + 3 < n) row_ptr[i0 + 4] = ex + p3;
        carry += chunk_total;
    }
    if (threadIdx.x == 0) row_ptr[0] = 0;
}

__global__ void fill_kernel(const int* __restrict__ src, const int* __restrict__ dst,
                            int* __restrict__ cursor, int* __restrict__ col, int E) {
    int i = blockIdx.x * blockDim.x + threadIdx.x;
    if (i < E) {
        int d_ = dst[i];
        int pos = atomicAdd(&cursor[d_], 1);
        col[pos] = src[i];
    }
}

// ---------------- Wx = x @ W1^T + b1 ----------------

__global__ __launch_bounds__(64) void wx_kernel(const float* __restrict__ x,
                                                const float* __restrict__ W1,
                                                const float* __restrict__ b1,
                                                float* __restrict__ Wx, int N) {
    __shared__ float xr[F];
    int v = blockIdx.x;
    if (v >= N) return;
    int t = threadIdx.x;  // 0..63
    xr[t]      = x[(size_t)v * F + t];
    xr[t + 64] = x[(size_t)v * F + 64 + t];
    __syncthreads();
    float acc = b1[t];
    const float4* w4 = reinterpret_cast<const float4*>(W1 + (size_t)t * F);
    const float4* x4 = reinterpret_cast<const float4*>(xr);
    #pragma unroll
    for (int k = 0; k < F / 4; ++k) {
        float4 wv = w4[k];
        float4 xv = x4[k];
        acc += wv.x * xv.x + wv.y * xv.y + wv.z * xv.z + wv.w * xv.w;
    }
    Wx[(size_t)v * D + t] = acc;
}

// emb1 = relu(Wx + b2)   (iteration 1: agg == 0)
__global__ void init_kernel(const float* __restrict__ Wx, const float* __restrict__ b2,
                            float* __restrict__ emb, int total) {
    int i = blockIdx.x * blockDim.x + threadIdx.x;
    if (i < total) {
        float r = Wx[i] + b2[i & (D - 1)];
        emb[i] = r > 0.f ? r : 0.f;
    }
}

// ---------------- fused iteration: emb_out = relu(Wx + (gather-sum)@W2^T + b2) ----------------

__global__ __launch_bounds__(256) void step_kernel(const float* __restrict__ emb_in,
                                                   float* __restrict__ emb_out,
                                                   const float* __restrict__ Wx,
                                                   const float* __restrict__ W2,
                                                   const float* __restrict__ b2,
                                                   const int* __restrict__ row_ptr,
                                                   const int* __restrict__ col, int N) {
    int lane = threadIdx.x & 63;
    int wid  = threadIdx.x >> 6;
    // W2 row for this lane lives in registers for the whole kernel (persistent blocks).
    float w2r[D];
    #pragma unroll
    for (int k = 0; k < D / 4; ++k) {
        float4 t = reinterpret_cast<const float4*>(W2 + (size_t)lane * D)[k];
        w2r[4 * k] = t.x; w2r[4 * k + 1] = t.y; w2r[4 * k + 2] = t.z; w2r[4 * k + 3] = t.w;
    }
    float b2v = b2[lane];
    int nw = gridDim.x * 4;
    for (int v = blockIdx.x * 4 + wid; v < N; v += nw) {
        int s = row_ptr[v], e = row_ptr[v + 1];
        float acc = 0.f;  // lane holds agg[v][lane]
        int k = s;
        for (; k + 4 <= e; k += 4) {
            int u0 = col[k], u1 = col[k + 1], u2 = col[k + 2], u3 = col[k + 3];
            float a0 = emb_in[(size_t)u0 * D + lane];
            float a1 = emb_in[(size_t)u1 * D + lane];
            float a2 = emb_in[(size_t)u2 * D + lane];
            float a3 = emb_in[(size_t)u3 * D + lane];
            acc += a0 + a1 + a2 + a3;
        }
        for (; k < e; ++k) acc += emb_in[(size_t)col[k] * D + lane];
        // r[d] = Wx[v][d] + b2[d] + sum_k agg[k] * W2[d][k]
        float r = Wx[(size_t)v * D + lane] + b2v;
        #pragma unroll
        for (int kk = 0; kk < D; ++kk) {
            r += __shfl(acc, kk) * w2r[kk];
        }
        emb_out[(size_t)v * D + lane] = r > 0.f ? r : 0.f;
    }
}

// ---------------- final: out[d] = sum_v emb[v][d] ----------------

__global__ __launch_bounds__(256) void reduce_kernel(const float* __restrict__ emb,
                                                     float* __restrict__ out, int N) {
    int lane = threadIdx.x & 63;
    int wid  = threadIdx.x >> 6;
    float acc = 0.f;
    int nw = gridDim.x * 4;
    for (int v = blockIdx.x * 4 + wid; v < N; v += nw)
        acc += emb[(size_t)v * D + lane];
    __shared__ float red[256];
    red[threadIdx.x] = acc;
    __syncthreads();
    if (threadIdx.x < 64) {
        float s = red[threadIdx.x] + red[threadIdx.x + 64] +
                  red[threadIdx.x + 128] + red[threadIdx.x + 192];
        atomicAdd(&out[threadIdx.x], s);
    }
}

extern "C" void kernel_launch(void* const* d_in, const int* in_sizes, int n_in,
                              void* d_out, int out_size, void* d_ws, size_t ws_size,
                              hipStream_t stream) {
    const float* x    = (const float*)d_in[0];
    const float* W1   = (const float*)d_in[1];
    const float* b1   = (const float*)d_in[2];
    const float* W2   = (const float*)d_in[3];
    const float* b2   = (const float*)d_in[4];
    const int*   esrc = (const int*)d_in[5];
    const int*   edst = (const int*)d_in[6];
    int N = in_sizes[0] / F;
    int E = in_sizes[5];
    float* out = (float*)d_out;

    char* ws = (char*)d_ws;
    size_t off = 0;
    auto alloc = [&](size_t bytes) -> char* {
        char* p = ws + off;
        off += (bytes + 255) & ~(size_t)255;
        return p;
    };
    float* Wx      = (float*)alloc((size_t)N * D * 4);
    float* embA    = (float*)alloc((size_t)N * D * 4);
    float* embB    = (float*)alloc((size_t)N * D * 4);
    int*   row_ptr = (int*)alloc(((size_t)N + 1) * 4);
    int*   cursor  = (int*)alloc((size_t)N * 4);
    int*   deg     = (int*)alloc((size_t)N * 4);
    int*   col     = (int*)alloc((size_t)E * 4);

    hipMemsetAsync(deg, 0, (size_t)N * 4, stream);
    hipMemsetAsync(out, 0, (size_t)out_size * 4, stream);

    count_deg_kernel<<<(E + 255) / 256, 256, 0, stream>>>(edst, deg, E);
    scan_kernel<<<1, 1024, 0, stream>>>(deg, row_ptr, N);
    hipMemcpyAsync(cursor, row_ptr, (size_t)N * 4, hipMemcpyDeviceToDevice, stream);
    fill_kernel<<<(E + 255) / 256, 256, 0, stream>>>(esrc, edst, cursor, col, E);

    wx_kernel<<<N, 64, 0, stream>>>(x, W1, b1, Wx, N);
    init_kernel<<<(N * D + 255) / 256, 256, 0, stream>>>(Wx, b2, embA, N * D);

    float* pin = embA;
    float* pout = embB;
    for (int t = 1; t < 10; ++t) {  // iterations 2..10
        step_kernel<<<2048, 256, 0, stream>>>(pin, pout, Wx, W2, b2, row_ptr, col, N);
        float* tmp = pin; pin = pout; pout = tmp;
    }
    reduce_kernel<<<256, 256, 0, stream>>>(pin, out, N);
}

// Round 2
// 1214.216 us; speedup vs baseline: 1.1597x; 1.1597x over previous
//
#include <hip/hip_runtime.h>

#define D 64
#define F 128

// ---------------- CSR build (rows padded to multiple of 4; pad entries -> zero row N) ----------------

__global__ void count_deg_kernel(const int* __restrict__ dst, int* __restrict__ deg, int E) {
    int i = blockIdx.x * blockDim.x + threadIdx.x;
    if (i < E) atomicAdd(&deg[dst[i]], 1);
}

// Single-block prefix scan over PADDED degrees: row_ptr[0]=0, row_ptr[i+1]=sum of ceil4(deg[0..i]).
__global__ __launch_bounds__(1024) void scan_kernel(const int* __restrict__ deg,
                                                    int* __restrict__ row_ptr, int n) {
    __shared__ int wsum[16];
    int lane = threadIdx.x & 63;
    int wid  = threadIdx.x >> 6;
    int carry = 0;
    const int CH = 4096;  // 1024 threads x 4 elements
    for (int base = 0; base < n; base += CH) {
        int i0 = base + (int)threadIdx.x * 4;
        int v0 = (i0     < n) ? ((deg[i0]     + 3) & ~3) : 0;
        int v1 = (i0 + 1 < n) ? ((deg[i0 + 1] + 3) & ~3) : 0;
        int v2 = (i0 + 2 < n) ? ((deg[i0 + 2] + 3) & ~3) : 0;
        int v3 = (i0 + 3 < n) ? ((deg[i0 + 3] + 3) & ~3) : 0;
        int p0 = v0, p1 = p0 + v1, p2 = p1 + v2, p3 = p2 + v3;
        int tsum = p3;
        int s = tsum;
        #pragma unroll
        for (int off = 1; off < 64; off <<= 1) {
            int t = __shfl_up(s, off);
            if (lane >= off) s += t;
        }
        if (lane == 63) wsum[wid] = s;
        __syncthreads();
        int wbase = 0, chunk_total = 0;
        #pragma unroll
        for (int w = 0; w < 16; ++w) {
            int t = wsum[w];
            chunk_total += t;
            if (w < wid) wbase += t;
        }
        __syncthreads();
        int ex = carry + wbase + (s - tsum);
        if (i0     < n) row_ptr[i0 + 1] = ex + p0;
        if (i0 + 1 < n) row_ptr[i0 + 2] = ex + p1;
        if (i0 + 2 < n) row_ptr[i0 + 3] = ex + p2;
        if (i0 + 3 < n) row_ptr[i0 + 4] = ex + p3;
        carry += chunk_total;
    }
    if (threadIdx.x == 0) row_ptr[0] = 0;
}

__global__ void fill_kernel(const int* __restrict__ src, const int* __restrict__ dst,
                            int* __restrict__ cursor, int* __restrict__ col, int E) {
    int i = blockIdx.x * blockDim.x + threadIdx.x;
    if (i < E) {
        int d_ = dst[i];
        int pos = atomicAdd(&cursor[d_], 1);
        col[pos] = src[i];
    }
}

__global__ void pad_kernel(const int* __restrict__ row_ptr, const int* __restrict__ deg,
                           int* __restrict__ col, int N) {
    int v = blockIdx.x * blockDim.x + threadIdx.x;
    if (v < N) {
        int st = row_ptr[v] + deg[v];
        int en = row_ptr[v + 1];
        for (int k = st; k < en; ++k) col[k] = N;  // zero row
    }
}

// ---------------- Wx = x @ W1^T + b1 : W1^T staged in LDS, node per wave ----------------

__global__ __launch_bounds__(256) void wx_kernel(const float* __restrict__ x,
                                                 const float* __restrict__ W1,
                                                 const float* __restrict__ b1,
                                                 float* __restrict__ Wx, int N) {
    __shared__ float w1t[F][D];  // 32 KiB, transposed: w1t[k][d]
    int t = threadIdx.x;
    {
        int d  = t >> 2;         // 0..63
        int k0 = (t & 3) * 32;   // 0,32,64,96
        const float4* src = reinterpret_cast<const float4*>(W1 + (size_t)d * F + k0);
        #pragma unroll
        for (int j = 0; j < 8; ++j) {
            float4 w = src[j];
            int k = k0 + j * 4;
            w1t[k][d] = w.x; w1t[k + 1][d] = w.y; w1t[k + 2][d] = w.z; w1t[k + 3][d] = w.w;
        }
    }
    __syncthreads();
    int lane = t & 63, wid = t >> 6;
    float b = b1[lane];
    int nw = gridDim.x * 4;
    for (int v = blockIdx.x * 4 + wid; v < N; v += nw) {
        float2 x2 = reinterpret_cast<const float2*>(x + (size_t)v * F)[lane];  // x[2*lane], x[2*lane+1]
        float acc = b;
        #pragma unroll
        for (int k = 0; k < F; k += 2) {
            float xa = __shfl(x2.x, k >> 1);
            float xb = __shfl(x2.y, k >> 1);
            acc += xa * w1t[k][lane] + xb * w1t[k + 1][lane];
        }
        Wx[(size_t)v * D + lane] = acc;
    }
}

// emb1 = relu(Wx + b2)
__global__ void init_kernel(const float* __restrict__ Wx, const float* __restrict__ b2,
                            float* __restrict__ emb, int total) {
    int i = blockIdx.x * blockDim.x + threadIdx.x;
    if (i < total) {
        float r = Wx[i] + b2[i & (D - 1)];
        emb[i] = r > 0.f ? r : 0.f;
    }
}

// ---------------- fused iteration ----------------
// lane = 16*g + s: group g handles neighbor slot (k+g), reading float4 of dims [4s..4s+3].

__global__ __launch_bounds__(256) void step_kernel(const float* __restrict__ emb_in,
                                                   float* __restrict__ emb_out,
                                                   const float* __restrict__ Wx,
                                                   const float* __restrict__ W2,
                                                   const float* __restrict__ b2,
                                                   const int* __restrict__ row_ptr,
                                                   const int* __restrict__ col, int N) {
    int lane = threadIdx.x & 63;
    int wid  = threadIdx.x >> 6;
    float w2r[D];
    #pragma unroll
    for (int k = 0; k < D / 4; ++k) {
        float4 t4 = reinterpret_cast<const float4*>(W2 + (size_t)lane * D)[k];
        w2r[4 * k] = t4.x; w2r[4 * k + 1] = t4.y; w2r[4 * k + 2] = t4.z; w2r[4 * k + 3] = t4.w;
    }
    float b2v = b2[lane];
    int g = lane >> 4;   // 0..3
    int s = lane & 15;   // 0..15
    int nw = gridDim.x * 4;
    for (int v = blockIdx.x * 4 + wid; v < N; v += nw) {
        int st = row_ptr[v], en = row_ptr[v + 1];  // multiple-of-4 range
        float4 acc = {0.f, 0.f, 0.f, 0.f};
        for (int k = st; k < en; k += 8) {
            int4 c0 = *reinterpret_cast<const int4*>(col + k);
            bool h2 = (k + 4 < en);
            int4 c1 = h2 ? *reinterpret_cast<const int4*>(col + k + 4) : (int4){N, N, N, N};
            int u0 = (g == 0) ? c0.x : (g == 1) ? c0.y : (g == 2) ? c0.z : c0.w;
            int u1 = (g == 0) ? c1.x : (g == 1) ? c1.y : (g == 2) ? c1.z : c1.w;
            float4 a0 = reinterpret_cast<const float4*>(emb_in + (size_t)u0 * D)[s];
            float4 a1 = reinterpret_cast<const float4*>(emb_in + (size_t)u1 * D)[s];
            acc.x += a0.x + a1.x; acc.y += a0.y + a1.y;
            acc.z += a0.z + a1.z; acc.w += a0.w + a1.w;
        }
        // combine the 4 neighbor groups (lanes 16 apart hold same dims)
        #pragma unroll
        for (int off = 16; off < 64; off <<= 1) {
            acc.x += __shfl_xor(acc.x, off);
            acc.y += __shfl_xor(acc.y, off);
            acc.z += __shfl_xor(acc.z, off);
            acc.w += __shfl_xor(acc.w, off);
        }
        // lane s (replicated across groups) holds agg[4s..4s+3]; broadcast and matvec
        float r = Wx[(size_t)v * D + lane] + b2v;
        #pragma unroll
        for (int kk = 0; kk < D; ++kk) {
            float a = __shfl((kk & 3) == 0 ? acc.x : (kk & 3) == 1 ? acc.y
                           : (kk & 3) == 2 ? acc.z : acc.w, kk >> 2);
            r += a * w2r[kk];
        }
        emb_out[(size_t)v * D + lane] = r > 0.f ? r : 0.f;
    }
}

// ---------------- final: out[d] = sum_v emb[v][d] ----------------

__global__ __launch_bounds__(256) void reduce_kernel(const float* __restrict__ emb,
                                                     float* __restrict__ out, int N) {
    int lane = threadIdx.x & 63;
    int wid  = threadIdx.x >> 6;
    float acc = 0.f;
    int nw = gridDim.x * 4;
    for (int v = blockIdx.x * 4 + wid; v < N; v += nw)
        acc += emb[(size_t)v * D + lane];
    __shared__ float red[256];
    red[threadIdx.x] = acc;
    __syncthreads();
    if (threadIdx.x < 64) {
        float sum = red[threadIdx.x] + red[threadIdx.x + 64] +
                    red[threadIdx.x + 128] + red[threadIdx.x + 192];
        atomicAdd(&out[threadIdx.x], sum);
    }
}

extern "C" void kernel_launch(void* const* d_in, const int* in_sizes, int n_in,
                              void* d_out, int out_size, void* d_ws, size_t ws_size,
                              hipStream_t stream) {
    const float* x    = (const float*)d_in[0];
    const float* W1   = (const float*)d_in[1];
    const float* b1   = (const float*)d_in[2];
    const float* W2   = (const float*)d_in[3];
    const float* b2   = (const float*)d_in[4];
    const int*   esrc = (const int*)d_in[5];
    const int*   edst = (const int*)d_in[6];
    int N = in_sizes[0] / F;
    int E = in_sizes[5];
    float* out = (float*)d_out;

    char* ws = (char*)d_ws;
    size_t off = 0;
    auto alloc = [&](size_t bytes) -> char* {
        char* p = ws + off;
        off += (bytes + 255) & ~(size_t)255;
        return p;
    };
    float* Wx      = (float*)alloc((size_t)N * D * 4);
    float* embA    = (float*)alloc(((size_t)N + 1) * D * 4);  // +1 zero row
    float* embB    = (float*)alloc(((size_t)N + 1) * D * 4);
    int*   row_ptr = (int*)alloc(((size_t)N + 1) * 4);
    int*   cursor  = (int*)alloc((size_t)N * 4);
    int*   deg     = (int*)alloc((size_t)N * 4);
    int*   col     = (int*)alloc(((size_t)E + 3 * (size_t)N) * 4);

    hipMemsetAsync(deg, 0, (size_t)N * 4, stream);
    hipMemsetAsync(out, 0, (size_t)out_size * 4, stream);
    hipMemsetAsync(embA + (size_t)N * D, 0, D * 4, stream);  // zero row N
    hipMemsetAsync(embB + (size_t)N * D, 0, D * 4, stream);

    count_deg_kernel<<<(E + 255) / 256, 256, 0, stream>>>(edst, deg, E);
    scan_kernel<<<1, 1024, 0, stream>>>(deg, row_ptr, N);
    hipMemcpyAsync(cursor, row_ptr, (size_t)N * 4, hipMemcpyDeviceToDevice, stream);
    fill_kernel<<<(E + 255) / 256, 256, 0, stream>>>(esrc, edst, cursor, col, E);
    pad_kernel<<<(N + 255) / 256, 256, 0, stream>>>(row_ptr, deg, col, N);

    wx_kernel<<<1024, 256, 0, stream>>>(x, W1, b1, Wx, N);
    init_kernel<<<(N * D + 255) / 256, 256, 0, stream>>>(Wx, b2, embA, N * D);

    float* pin = embA;
    float* pout = embB;
    for (int t = 1; t < 10; ++t) {
        step_kernel<<<2048, 256, 0, stream>>>(pin, pout, Wx, W2, b2, row_ptr, col, N);
        float* tmp = pin; pin = pout; pout = tmp;
    }
    reduce_kernel<<<256, 256, 0, stream>>>(pin, out, N);
}

// Round 3
// 889.475 us; speedup vs baseline: 1.5831x; 1.3651x over previous
//
#include <hip/hip_runtime.h>

#define D 64
#define F 128
#define NBMAX 256

typedef unsigned int uint;
typedef unsigned short ushort;

__device__ __forceinline__ float bf16lo(uint u) {
    return __uint_as_float(u << 16);
}
__device__ __forceinline__ float bf16hi(uint u) {
    return __uint_as_float(u & 0xFFFF0000u);
}
__device__ __forceinline__ ushort f2bf16(float f) {
    uint u = __float_as_uint(f);
    u += 0x7FFFu + ((u >> 16) & 1u);   // RNE
    return (ushort)(u >> 16);
}

// ================= bucketed CSR build (N <= 65536 path) =================
// bucket = dst >> 8 (256 nodes per bucket). packed edge = (src << 8) | (dst & 255).

__global__ __launch_bounds__(256) void bucket_hist(const int* __restrict__ dst,
                                                   int* __restrict__ gb, int E, int nb) {
    __shared__ int h[NBMAX];
    for (int t = threadIdx.x; t < nb; t += 256) h[t] = 0;
    __syncthreads();
    int start = blockIdx.x * 4096;
    int end   = start + 4096 < E ? start + 4096 : E;
    for (int i = start + threadIdx.x; i < end; i += 256)
        atomicAdd(&h[dst[i] >> 8], 1);
    __syncthreads();
    for (int t = threadIdx.x; t < nb; t += 256)
        if (h[t]) atomicAdd(&gb[t], h[t]);
}

__global__ void bucket_scan(const int* __restrict__ gb, int* __restrict__ gboff,
                            int* __restrict__ gcur, int nb) {
    if (threadIdx.x == 0) {
        int s = 0;
        for (int b = 0; b < nb; ++b) { gboff[b] = s; gcur[b] = s; s += gb[b]; }
        gboff[nb] = s;
    }
}

__global__ __launch_bounds__(256) void bucket_scatter(const int* __restrict__ src,
                                                      const int* __restrict__ dst,
                                                      int* __restrict__ gcur,
                                                      int* __restrict__ packed, int E, int nb) {
    __shared__ int h[NBMAX], base[NBMAX], lcur[NBMAX];
    for (int t = threadIdx.x; t < nb; t += 256) h[t] = 0;
    __syncthreads();
    int start = blockIdx.x * 4096;
    int end   = start + 4096 < E ? start + 4096 : E;
    for (int i = start + threadIdx.x; i < end; i += 256)
        atomicAdd(&h[dst[i] >> 8], 1);
    __syncthreads();
    for (int t = threadIdx.x; t < nb; t += 256) {
        base[t] = h[t] ? atomicAdd(&gcur[t], h[t]) : 0;
        lcur[t] = 0;
    }
    __syncthreads();
    for (int i = start + threadIdx.x; i < end; i += 256) {
        int d = dst[i];
        int b = d >> 8;
        int pos = base[b] + atomicAdd(&lcur[b], 1);
        packed[pos] = (src[i] << 8) | (d & 255);
    }
}

__global__ __launch_bounds__(256) void bucket_deg(const int* __restrict__ gboff,
                                                  const int* __restrict__ packed,
                                                  int* __restrict__ deg, int N) {
    __shared__ int h[NBMAX];
    int b = blockIdx.x;
    h[threadIdx.x] = 0;
    __syncthreads();
    int st = gboff[b], en = gboff[b + 1];
    for (int i = st + threadIdx.x; i < en; i += 256)
        atomicAdd(&h[packed[i] & 255], 1);
    __syncthreads();
    int node = (b << 8) + threadIdx.x;
    if (node < N) deg[node] = h[threadIdx.x];
}

__global__ __launch_bounds__(256) void bucket_fill(const int* __restrict__ gboff,
                                                   const int* __restrict__ packed,
                                                   const int* __restrict__ row_ptr,
                                                   int* __restrict__ col, int N) {
    __shared__ int lcur[NBMAX];
    int b = blockIdx.x;
    int node = (b << 8) + threadIdx.x;
    lcur[threadIdx.x] = (node < N) ? row_ptr[node] : 0;
    __syncthreads();
    int st = gboff[b], en = gboff[b + 1];
    for (int i = st + threadIdx.x; i < en; i += 256) {
        int p = packed[i];
        int pos = atomicAdd(&lcur[p & 255], 1);
        col[pos] = p >> 8;
    }
}

// ================= fallback CSR build (N > 65536) =================

__global__ void count_deg_kernel(const int* __restrict__ dst, int* __restrict__ deg, int E) {
    int i = blockIdx.x * blockDim.x + threadIdx.x;
    if (i < E) atomicAdd(&deg[dst[i]], 1);
}

__global__ void fill_kernel(const int* __restrict__ src, const int* __restrict__ dst,
                            int* __restrict__ cursor, int* __restrict__ col, int E) {
    int i = blockIdx.x * blockDim.x + threadIdx.x;
    if (i < E) {
        int d_ = dst[i];
        int pos = atomicAdd(&cursor[d_], 1);
        col[pos] = src[i];
    }
}

// ================= row_ptr scan (padded deg to multiple of 8) =================

__global__ __launch_bounds__(1024) void scan_kernel(const int* __restrict__ deg,
                                                    int* __restrict__ row_ptr, int n) {
    __shared__ int wsum[16];
    int lane = threadIdx.x & 63;
    int wid  = threadIdx.x >> 6;
    int carry = 0;
    const int CH = 4096;
    for (int base = 0; base < n; base += CH) {
        int i0 = base + (int)threadIdx.x * 4;
        int v0 = (i0     < n) ? ((deg[i0]     + 7) & ~7) : 0;
        int v1 = (i0 + 1 < n) ? ((deg[i0 + 1] + 7) & ~7) : 0;
        int v2 = (i0 + 2 < n) ? ((deg[i0 + 2] + 7) & ~7) : 0;
        int v3 = (i0 + 3 < n) ? ((deg[i0 + 3] + 7) & ~7) : 0;
        int p0 = v0, p1 = p0 + v1, p2 = p1 + v2, p3 = p2 + v3;
        int tsum = p3;
        int s = tsum;
        #pragma unroll
        for (int off = 1; off < 64; off <<= 1) {
            int t = __shfl_up(s, off);
            if (lane >= off) s += t;
        }
        if (lane == 63) wsum[wid] = s;
        __syncthreads();
        int wbase = 0, chunk_total = 0;
        #pragma unroll
        for (int w = 0; w < 16; ++w) {
            int t = wsum[w];
            chunk_total += t;
            if (w < wid) wbase += t;
        }
        __syncthreads();
        int ex = carry + wbase + (s - tsum);
        if (i0     < n) row_ptr[i0 + 1] = ex + p0;
        if (i0 + 1 < n) row_ptr[i0 + 2] = ex + p1;
        if (i0 + 2 < n) row_ptr[i0 + 3] = ex + p2;
        if (i0 + 3 < n) row_ptr[i0 + 4] = ex + p3;
        carry += chunk_total;
    }
    if (threadIdx.x == 0) row_ptr[0] = 0;
}

__global__ void pad_kernel(const int* __restrict__ row_ptr, const int* __restrict__ deg,
                           int* __restrict__ col, int N) {
    int v = blockIdx.x * blockDim.x + threadIdx.x;
    if (v < N) {
        int st = row_ptr[v] + deg[v];
        int en = row_ptr[v + 1];
        for (int k = st; k < en; ++k) col[k] = N;  // zero row
    }
}

// ================= Wx = x @ W1^T + b1 (f32) =================

__global__ __launch_bounds__(256) void wx_kernel(const float* __restrict__ x,
                                                 const float* __restrict__ W1,
                                                 const float* __restrict__ b1,
                                                 float* __restrict__ Wx, int N) {
    __shared__ float w1t[F][D];
    int t = threadIdx.x;
    {
        int d  = t >> 2;
        int k0 = (t & 3) * 32;
        const float4* src = reinterpret_cast<const float4*>(W1 + (size_t)d * F + k0);
        #pragma unroll
        for (int j = 0; j < 8; ++j) {
            float4 w = src[j];
            int k = k0 + j * 4;
            w1t[k][d] = w.x; w1t[k + 1][d] = w.y; w1t[k + 2][d] = w.z; w1t[k + 3][d] = w.w;
        }
    }
    __syncthreads();
    int lane = t & 63, wid = t >> 6;
    float b = b1[lane];
    int nw = gridDim.x * 4;
    for (int v = blockIdx.x * 4 + wid; v < N; v += nw) {
        float2 x2 = reinterpret_cast<const float2*>(x + (size_t)v * F)[lane];
        float acc = b;
        #pragma unroll
        for (int k = 0; k < F; k += 2) {
            float xa = __shfl(x2.x, k >> 1);
            float xb = __shfl(x2.y, k >> 1);
            acc += xa * w1t[k][lane] + xb * w1t[k + 1][lane];
        }
        Wx[(size_t)v * D + lane] = acc;
    }
}

// emb1 = relu(Wx + b2), stored bf16
__global__ void init_kernel(const float* __restrict__ Wx, const float* __restrict__ b2,
                            ushort* __restrict__ emb, int total) {
    int i = blockIdx.x * blockDim.x + threadIdx.x;
    if (i < total) {
        float r = Wx[i] + b2[i & (D - 1)];
        emb[i] = f2bf16(r > 0.f ? r : 0.f);
    }
}

// ================= fused iteration (bf16 emb) =================
// lane = 8*g + s: group g handles neighbor slot k+g; lane reads 16B = 8 bf16 dims [8s..8s+7].

__global__ __launch_bounds__(256) void step_kernel(const ushort* __restrict__ emb_in,
                                                   ushort* __restrict__ emb_out,
                                                   const float* __restrict__ Wx,
                                                   const float* __restrict__ W2,
                                                   const float* __restrict__ b2,
                                                   const int* __restrict__ row_ptr,
                                                   const int* __restrict__ col, int N) {
    int lane = threadIdx.x & 63;
    int wid  = threadIdx.x >> 6;
    float w2r[D];
    #pragma unroll
    for (int k = 0; k < D / 4; ++k) {
        float4 t4 = reinterpret_cast<const float4*>(W2 + (size_t)lane * D)[k];
        w2r[4 * k] = t4.x; w2r[4 * k + 1] = t4.y; w2r[4 * k + 2] = t4.z; w2r[4 * k + 3] = t4.w;
    }
    float b2v = b2[lane];
    int g = lane >> 3;   // 0..7 neighbor slot
    int s = lane & 7;    // 0..7 dim block
    int nw = gridDim.x * 4;
    for (int v = blockIdx.x * 4 + wid; v < N; v += nw) {
        int st = row_ptr[v], en = row_ptr[v + 1];  // multiple of 8
        float a0 = 0.f, a1 = 0.f, a2 = 0.f, a3 = 0.f, a4 = 0.f, a5 = 0.f, a6 = 0.f, a7 = 0.f;
        for (int k = st; k < en; k += 8) {
            int u = col[k + g];
            uint4 q = reinterpret_cast<const uint4*>(emb_in + ((size_t)u << 6))[s];
            a0 += bf16lo(q.x); a1 += bf16hi(q.x);
            a2 += bf16lo(q.y); a3 += bf16hi(q.y);
            a4 += bf16lo(q.z); a5 += bf16hi(q.z);
            a6 += bf16lo(q.w); a7 += bf16hi(q.w);
        }
        // reduce across the 8 neighbor groups (lanes 8 apart hold same dims)
        #pragma unroll
        for (int off = 8; off < 64; off <<= 1) {
            a0 += __shfl_xor(a0, off); a1 += __shfl_xor(a1, off);
            a2 += __shfl_xor(a2, off); a3 += __shfl_xor(a3, off);
            a4 += __shfl_xor(a4, off); a5 += __shfl_xor(a5, off);
            a6 += __shfl_xor(a6, off); a7 += __shfl_xor(a7, off);
        }
        // lane s holds agg[8s..8s+7] (replicated across groups); broadcast + matvec
        float r = Wx[(size_t)v * D + lane] + b2v;
        #pragma unroll
        for (int kk = 0; kk < D; ++kk) {
            float a;
            switch (kk & 7) {
                case 0: a = __shfl(a0, kk >> 3); break;
                case 1: a = __shfl(a1, kk >> 3); break;
                case 2: a = __shfl(a2, kk >> 3); break;
                case 3: a = __shfl(a3, kk >> 3); break;
                case 4: a = __shfl(a4, kk >> 3); break;
                case 5: a = __shfl(a5, kk >> 3); break;
                case 6: a = __shfl(a6, kk >> 3); break;
                default: a = __shfl(a7, kk >> 3); break;
            }
            r += a * w2r[kk];
        }
        emb_out[(size_t)v * D + lane] = f2bf16(r > 0.f ? r : 0.f);
    }
}

// ================= final: out[d] = sum_v emb[v][d] =================

__global__ __launch_bounds__(256) void reduce_kernel(const ushort* __restrict__ emb,
                                                     float* __restrict__ out, int N) {
    int lane = threadIdx.x & 63;
    int wid  = threadIdx.x >> 6;
    float acc = 0.f;
    int nw = gridDim.x * 4;
    for (int v = blockIdx.x * 4 + wid; v < N; v += nw)
        acc += __uint_as_float((uint)emb[(size_t)v * D + lane] << 16);
    __shared__ float red[256];
    red[threadIdx.x] = acc;
    __syncthreads();
    if (threadIdx.x < 64) {
        float sum = red[threadIdx.x] + red[threadIdx.x + 64] +
                    red[threadIdx.x + 128] + red[threadIdx.x + 192];
        atomicAdd(&out[threadIdx.x], sum);
    }
}

extern "C" void kernel_launch(void* const* d_in, const int* in_sizes, int n_in,
                              void* d_out, int out_size, void* d_ws, size_t ws_size,
                              hipStream_t stream) {
    const float* x    = (const float*)d_in[0];
    const float* W1   = (const float*)d_in[1];
    const float* b1   = (const float*)d_in[2];
    const float* W2   = (const float*)d_in[3];
    const float* b2   = (const float*)d_in[4];
    const int*   esrc = (const int*)d_in[5];
    const int*   edst = (const int*)d_in[6];
    int N = in_sizes[0] / F;
    int E = in_sizes[5];
    float* out = (float*)d_out;

    char* ws = (char*)d_ws;
    size_t off = 0;
    auto alloc = [&](size_t bytes) -> char* {
        char* p = ws + off;
        off += (bytes + 255) & ~(size_t)255;
        return p;
    };
    float*  Wx      = (float*)alloc((size_t)N * D * 4);
    ushort* embA    = (ushort*)alloc(((size_t)N + 1) * D * 2);
    ushort* embB    = (ushort*)alloc(((size_t)N + 1) * D * 2);
    int*    row_ptr = (int*)alloc(((size_t)N + 1) * 4);
    int*    deg     = (int*)alloc((size_t)N * 4);
    int*    col     = (int*)alloc(((size_t)E + 7 * (size_t)N) * 4);
    int*    packed  = (int*)alloc((size_t)E * 4);
    int*    gb      = (int*)alloc((NBMAX + 1) * 4);
    int*    gboff   = (int*)alloc((NBMAX + 1) * 4);
    int*    gcur    = (int*)alloc((NBMAX + 1) * 4);
    int*    cursor  = (int*)alloc((size_t)N * 4);  // fallback path only

    hipMemsetAsync(out, 0, (size_t)out_size * 4, stream);
    hipMemsetAsync(embA + (size_t)N * D, 0, D * 2, stream);
    hipMemsetAsync(embB + (size_t)N * D, 0, D * 2, stream);

    int nb = ((N - 1) >> 8) + 1;
    int nchunks = (E + 4095) / 4096;
    if (N <= 65536) {
        hipMemsetAsync(gb, 0, (size_t)nb * 4, stream);
        bucket_hist<<<nchunks, 256, 0, stream>>>(edst, gb, E, nb);
        bucket_scan<<<1, 64, 0, stream>>>(gb, gboff, gcur, nb);
        bucket_scatter<<<nchunks, 256, 0, stream>>>(esrc, edst, gcur, packed, E, nb);
        bucket_deg<<<nb, 256, 0, stream>>>(gboff, packed, deg, N);
        scan_kernel<<<1, 1024, 0, stream>>>(deg, row_ptr, N);
        bucket_fill<<<nb, 256, 0, stream>>>(gboff, packed, row_ptr, col, N);
    } else {
        hipMemsetAsync(deg, 0, (size_t)N * 4, stream);
        count_deg_kernel<<<(E + 255) / 256, 256, 0, stream>>>(edst, deg, E);
        scan_kernel<<<1, 1024, 0, stream>>>(deg, row_ptr, N);
        hipMemcpyAsync(cursor, row_ptr, (size_t)N * 4, hipMemcpyDeviceToDevice, stream);
        fill_kernel<<<(E + 255) / 256, 256, 0, stream>>>(esrc, edst, cursor, col, E);
    }
    pad_kernel<<<(N + 255) / 256, 256, 0, stream>>>(row_ptr, deg, col, N);

    wx_kernel<<<1024, 256, 0, stream>>>(x, W1, b1, Wx, N);
    init_kernel<<<(N * D + 255) / 256, 256, 0, stream>>>(Wx, b2, embA, N * D);

    ushort* pin = embA;
    ushort* pout = embB;
    for (int t = 1; t < 10; ++t) {
        step_kernel<<<2048, 256, 0, stream>>>(pin, pout, Wx, W2, b2, row_ptr, col, N);
        ushort* tmp = pin; pin = pout; pout = tmp;
    }
    reduce_kernel<<<256, 256, 0, stream>>>(pin, out, N);
}